// Round 13
// baseline (165.970 us; speedup 1.0000x reference)
//
#include <hip/hip_runtime.h>
#include <stdint.h>

// Problem constants
#define BB 16
#define TT 4096
#define HH 64
#define MM 640    // HH*DD

// ---------------------------------------------------------------------------
// Kernel 1: ksum[b][m] = sum_t key[b][t][m]  (~27 us, near read roofline)
// ---------------------------------------------------------------------------
__global__ void __launch_bounds__(256)
ksum_kernel(const float* __restrict__ key, float* __restrict__ ksum) {
    int g = blockIdx.x * blockDim.x + threadIdx.x;   // b*160 + c
    int b = g / 160;
    int c = g % 160;
    int t0 = blockIdx.y * 32;

    const float4* p = reinterpret_cast<const float4*>(key)
                    + (size_t)b * TT * 160 + (size_t)t0 * 160 + c;

    float4 a0 = make_float4(0.f,0.f,0.f,0.f);
    float4 a1 = make_float4(0.f,0.f,0.f,0.f);
    float4 a2 = make_float4(0.f,0.f,0.f,0.f);
    float4 a3 = make_float4(0.f,0.f,0.f,0.f);
    #pragma unroll
    for (int i = 0; i < 32; i += 4) {
        float4 x0 = p[(size_t)(i + 0) * 160];
        float4 x1 = p[(size_t)(i + 1) * 160];
        float4 x2 = p[(size_t)(i + 2) * 160];
        float4 x3 = p[(size_t)(i + 3) * 160];
        a0.x += x0.x; a0.y += x0.y; a0.z += x0.z; a0.w += x0.w;
        a1.x += x1.x; a1.y += x1.y; a1.z += x1.z; a1.w += x1.w;
        a2.x += x2.x; a2.y += x2.y; a2.z += x2.z; a2.w += x2.w;
        a3.x += x3.x; a3.y += x3.y; a3.z += x3.z; a3.w += x3.w;
    }
    float sx = (a0.x + a1.x) + (a2.x + a3.x);
    float sy = (a0.y + a1.y) + (a2.y + a3.y);
    float sz = (a0.z + a1.z) + (a2.z + a3.z);
    float sw = (a0.w + a1.w) + (a2.w + a3.w);

    float* dst = ksum + b * MM + c * 4;
    atomicAdd(dst + 0, sx);
    atomicAdd(dst + 1, sy);
    atomicAdd(dst + 2, sz);
    atomicAdd(dst + 3, sw);
}

// ---------------------------------------------------------------------------
// Robust tanh via rcp (exp of negative arg only -> never overflows)
// ---------------------------------------------------------------------------
__device__ __forceinline__ float tanh_rcp(float x) {
    float ax = fabsf(x);
    float e2 = __expf(-2.0f * ax);
    float th = (1.0f - e2) * __builtin_amdgcn_rcpf(1.0f + e2);
    return copysignf(th, x);
}

// ---------------------------------------------------------------------------
// Kernel 2: wave-private pipelined streaming. NO __syncthreads, NO vmcnt(0)
// drain in the loop, ALL global ops coalesced (16 lines / wave-instruction).
//   block = (b, part): 4 waves; wave owns private 10KB LDS + 8 tiles of
//   2 t-rows x 2560B (full rows -> coalesced).
//   per iter: issue next tile's 10 f4 loads -> compute cur tile from LDS
//             (lane = head, ksr in regs) -> ds_write next (counted vmcnt).
//   outputs: 16 per lane in VGPRs; epilogue LDS-transpose -> 4 coalesced
//   f4 stores (16 lines/instr) instead of 16 scattered 64-line stores.
// ---------------------------------------------------------------------------
__global__ void __launch_bounds__(256)
attn_kernel(const float* __restrict__ q,
            const float* __restrict__ v,
            const float* __restrict__ ksum,
            float* __restrict__ out) {
    __shared__ float4 lds4[4][640];       // 10KB per wave, 40KB -> 4 blocks/CU

    const int tid  = threadIdx.x;
    const int w    = tid >> 6;
    const int lane = tid & 63;
    const int part = blockIdx.x & 63;     // 64 parts per batch
    const int b    = blockIdx.x >> 6;

    // per-lane head = lane; ksum row -> 10 regs, once (one-time gather, ~3MB)
    const float R = 0.316227766016838f;   // 1/sqrt(10)
    float ksr[10];
    {
        const float* ks = ksum + b * MM + lane * 10;
        #pragma unroll
        for (int d = 0; d < 10; ++d) ksr[d] = ks[d] * R;
    }

    const float4* q4 = (const float4*)q + (size_t)b * TT * 160;
    const float4* v4 = (const float4*)v + (size_t)b * TT * 160;

    float4* qb = &lds4[w][0];             // 320 f4 (2 rows)
    float4* vb = &lds4[w][320];
    const float* qf = (const float*)qb;
    const float* vf = (const float*)vb;

    const int T0 = part * 32 + w * 8;     // wave's first tile; 8 tiles, t contiguous
    float  oacc[16];
    float4 rq[5], rv[5];

    // ---- prologue: load + stage tile T0 ----
    {
        size_t g = (size_t)(T0 * 2) * 160;
        #pragma unroll
        for (int j = 0; j < 5; ++j) {
            rq[j] = q4[g + lane + 64 * j];
            rv[j] = v4[g + lane + 64 * j];
        }
        #pragma unroll
        for (int j = 0; j < 5; ++j) {
            qb[lane + 64 * j] = rq[j];
            vb[lane + 64 * j] = rv[j];
        }
    }

    #pragma unroll
    for (int i = 0; i < 8; ++i) {
        // ---- issue next tile's coalesced loads (pinned above compute) ----
        if (i < 7) {
            size_t g = (size_t)((T0 + i + 1) * 2) * 160;
            #pragma unroll
            for (int j = 0; j < 5; ++j) {
                rq[j] = q4[g + lane + 64 * j];
                rv[j] = v4[g + lane + 64 * j];
            }
        }
        __builtin_amdgcn_sched_barrier(0);

        // ---- compute current tile from wave-private LDS ----
        #pragma unroll
        for (int r = 0; r < 2; ++r) {
            const int fb = r * 640 + lane * 10;
            float sum = 0.f, dot = 0.f;
            #pragma unroll
            for (int d = 0; d < 10; ++d) {
                float e = __expf(tanh_rcp(qf[fb + d] * ksr[d]));
                sum += e;
                dot += e * vf[fb + d];
            }
            oacc[i * 2 + r] = dot * __builtin_amdgcn_rcpf(sum);
        }
        __builtin_amdgcn_sched_barrier(0);

        // ---- stage next tile (compiler inserts COUNTED vmcnt; in-order DS
        //      pipeline makes write-after-read within the wave safe) ----
        if (i < 7) {
            #pragma unroll
            for (int j = 0; j < 5; ++j) {
                qb[lane + 64 * j] = rq[j];
                vb[lane + 64 * j] = rv[j];
            }
        }
    }

    // ---- epilogue: transpose 64h x 16t via LDS, 4 coalesced f4 stores ----
    float* tb = (float*)qb;               // reuse wave region (4KB)
    #pragma unroll
    for (int s = 0; s < 16; ++s)
        tb[s * 64 + lane] = oacc[s];      // conflict-free writes

    const int tw0 = part * 64 + w * 16;   // wave's contiguous t-window
    float* ob = out + (size_t)b * HH * TT;
    #pragma unroll
    for (int j = 0; j < 4; ++j) {
        int s  = j * 64 + lane;
        int h  = s >> 2;
        int t4 = (s & 3) * 4;
        float4 o;
        o.x = tb[(t4 + 0) * 64 + h];
        o.y = tb[(t4 + 1) * 64 + h];
        o.z = tb[(t4 + 2) * 64 + h];
        o.w = tb[(t4 + 3) * 64 + h];
        *(float4*)(ob + (size_t)h * TT + tw0 + t4) = o;
    }
}

// ---------------------------------------------------------------------------
extern "C" void kernel_launch(void* const* d_in, const int* in_sizes, int n_in,
                              void* d_out, int out_size, void* d_ws, size_t ws_size,
                              hipStream_t stream) {
    const float* q = (const float*)d_in[0];
    const float* k = (const float*)d_in[1];
    const float* v = (const float*)d_in[2];
    // d_in[3] = W, d_in[4] = b : dead code (softmax over size-1 axis == 1)
    float* out  = (float*)d_out;
    float* ksum = (float*)d_ws;    // B*M floats = 40 KB

    hipMemsetAsync(d_ws, 0, (size_t)BB * MM * sizeof(float), stream);
    ksum_kernel<<<dim3(10, 128), dim3(256), 0, stream>>>(k, ksum);
    // 16 b x 64 parts = 1024 blocks = 4/CU exactly (40KB LDS each)
    attn_kernel<<<dim3(BB * 64), dim3(256), 0, stream>>>(q, v, ksum, out);
}

// Round 14
// 136.953 us; speedup vs baseline: 1.2119x; 1.2119x over previous
//
#include <hip/hip_runtime.h>
#include <stdint.h>

// Problem constants
#define BB 16
#define TT 4096
#define HH 64
#define MM 640    // HH*DD

#define ITERS 4   // t-window iterations per attn block

// ---------------------------------------------------------------------------
// Kernel 1: ksum[b][m] = sum_t key[b][t][m]  (~27 us, near read roofline)
// ---------------------------------------------------------------------------
__global__ void __launch_bounds__(256)
ksum_kernel(const float* __restrict__ key, float* __restrict__ ksum) {
    int g = blockIdx.x * blockDim.x + threadIdx.x;   // b*160 + c
    int b = g / 160;
    int c = g % 160;
    int t0 = blockIdx.y * 32;

    const float4* p = reinterpret_cast<const float4*>(key)
                    + (size_t)b * TT * 160 + (size_t)t0 * 160 + c;

    float4 a0 = make_float4(0.f,0.f,0.f,0.f);
    float4 a1 = make_float4(0.f,0.f,0.f,0.f);
    float4 a2 = make_float4(0.f,0.f,0.f,0.f);
    float4 a3 = make_float4(0.f,0.f,0.f,0.f);
    #pragma unroll
    for (int i = 0; i < 32; i += 4) {
        float4 x0 = p[(size_t)(i + 0) * 160];
        float4 x1 = p[(size_t)(i + 1) * 160];
        float4 x2 = p[(size_t)(i + 2) * 160];
        float4 x3 = p[(size_t)(i + 3) * 160];
        a0.x += x0.x; a0.y += x0.y; a0.z += x0.z; a0.w += x0.w;
        a1.x += x1.x; a1.y += x1.y; a1.z += x1.z; a1.w += x1.w;
        a2.x += x2.x; a2.y += x2.y; a2.z += x2.z; a2.w += x2.w;
        a3.x += x3.x; a3.y += x3.y; a3.z += x3.z; a3.w += x3.w;
    }
    float sx = (a0.x + a1.x) + (a2.x + a3.x);
    float sy = (a0.y + a1.y) + (a2.y + a3.y);
    float sz = (a0.z + a1.z) + (a2.z + a3.z);
    float sw = (a0.w + a1.w) + (a2.w + a3.w);

    float* dst = ksum + b * MM + c * 4;
    atomicAdd(dst + 0, sx);
    atomicAdd(dst + 1, sy);
    atomicAdd(dst + 2, sz);
    atomicAdd(dst + 3, sw);
}

// ---------------------------------------------------------------------------
// Robust tanh via rcp (exp of negative arg only -> never overflows)
// ---------------------------------------------------------------------------
__device__ __forceinline__ float tanh_rcp(float x) {
    float ax = fabsf(x);
    float e2 = __expf(-2.0f * ax);
    float th = (1.0f - e2) * __builtin_amdgcn_rcpf(1.0f + e2);
    return copysignf(th, x);
}

// ---------------------------------------------------------------------------
// Kernel 2: R11 structure, amortized. Block stages the b-uniform ksum table
// to LDS ONCE (one barrier), then runs 4 independent streaming iterations:
//   iter: 10 coalesced f4 loads (head-pair = 20 floats = 5 aligned f4 per
//         tensor) -> regs -> compute via compiler-COUNTED vmcnt -> 2 stores.
// No barriers / drains / sched pins in the loop; overlap comes from 20-32
// resident waves/CU + iteration independence (the ksum regime).
// ---------------------------------------------------------------------------
__global__ void __launch_bounds__(256)
attn_kernel(const float* __restrict__ q,
            const float* __restrict__ v,
            const float* __restrict__ ksum,
            float* __restrict__ out) {
    __shared__ float ks_lds[MM];                     // 2.56 KB

    const int tid = threadIdx.x;
    const int g   = blockIdx.x;                      // 0..2047
    const int b   = g >> 7;                          // 128 blocks per batch
    const int U0  = (g & 127) * (256 * ITERS);       // first unit of block

    // ---- stage ksum slice (block-uniform b), one barrier total ----
    if (tid < 160) {
        reinterpret_cast<float4*>(ks_lds)[tid] =
            reinterpret_cast<const float4*>(ksum + (size_t)b * MM)[tid];
    }
    __syncthreads();

    // hp is loop-invariant: (U0 + i*256 + tid) & 31 == tid & 31
    const int hp = tid & 31;                         // head pair 0..31
    const int tb = (U0 >> 5) + (tid >> 5);           // t for i=0

    const float R = 0.316227766016838f;              // 1/sqrt(10)
    float ksr[20];
    #pragma unroll
    for (int j = 0; j < 20; ++j) ksr[j] = ks_lds[hp * 20 + j] * R;

    const size_t qvoff = (size_t)b * TT * MM + hp * 20;
    const float* qb = q + qvoff;
    const float* vb = v + qvoff;
    float* ob = out + ((size_t)(b * HH + hp * 2)) * TT;

    for (int i = 0; i < ITERS; ++i) {
        const int t = tb + i * 8;                    // t-window advances by 8

        const float4* qp = reinterpret_cast<const float4*>(qb + (size_t)t * MM);
        const float4* vp = reinterpret_cast<const float4*>(vb + (size_t)t * MM);

        float4 rq[5], rv[5];
        #pragma unroll
        for (int j = 0; j < 5; ++j) {
            rq[j] = qp[j];
            rv[j] = vp[j];
        }

        const float* qf = reinterpret_cast<const float*>(rq);
        const float* vf = reinterpret_cast<const float*>(rv);

        float res[2];
        #pragma unroll
        for (int h = 0; h < 2; ++h) {
            float sum = 0.f, dot = 0.f;
            #pragma unroll
            for (int d = 0; d < 10; ++d) {
                int j = h * 10 + d;                  // compile-time constant
                float e = __expf(tanh_rcp(qf[j] * ksr[j]));
                sum += e;
                dot += e * vf[j];
            }
            res[h] = dot * __builtin_amdgcn_rcpf(sum);
        }

        ob[t]      = res[0];
        ob[TT + t] = res[1];
    }
}

// ---------------------------------------------------------------------------
extern "C" void kernel_launch(void* const* d_in, const int* in_sizes, int n_in,
                              void* d_out, int out_size, void* d_ws, size_t ws_size,
                              hipStream_t stream) {
    const float* q = (const float*)d_in[0];
    const float* k = (const float*)d_in[1];
    const float* v = (const float*)d_in[2];
    // d_in[3] = W, d_in[4] = b : dead code (softmax over size-1 axis == 1)
    float* out  = (float*)d_out;
    float* ksum = (float*)d_ws;    // B*M floats = 40 KB

    hipMemsetAsync(d_ws, 0, (size_t)BB * MM * sizeof(float), stream);
    ksum_kernel<<<dim3(10, 128), dim3(256), 0, stream>>>(k, ksum);
    // 16 b x 128 blocks x 256 thr x 4 iters = 2M units
    attn_kernel<<<dim3(2048), dim3(256), 0, stream>>>(q, v, ksum, out);
}

// Round 15
// 129.561 us; speedup vs baseline: 1.2810x; 1.0571x over previous
//
#include <hip/hip_runtime.h>
#include <stdint.h>

// Problem constants
#define BB 16
#define TT 4096
#define HH 64
#define MM 640    // HH*DD

#define PADF4 41            // LDS row stride in float4
#define ROWSF (PADF4 * 4)   // 164 floats per row

// ---------------------------------------------------------------------------
// Kernel 1: ksum[b][m] = sum_t key[b][t][m]  (~27 us, near read roofline)
// ---------------------------------------------------------------------------
__global__ void __launch_bounds__(256)
ksum_kernel(const float* __restrict__ key, float* __restrict__ ksum) {
    int g = blockIdx.x * blockDim.x + threadIdx.x;   // b*160 + c
    int b = g / 160;
    int c = g % 160;
    int t0 = blockIdx.y * 32;

    const float4* p = reinterpret_cast<const float4*>(key)
                    + (size_t)b * TT * 160 + (size_t)t0 * 160 + c;

    float4 a0 = make_float4(0.f,0.f,0.f,0.f);
    float4 a1 = make_float4(0.f,0.f,0.f,0.f);
    float4 a2 = make_float4(0.f,0.f,0.f,0.f);
    float4 a3 = make_float4(0.f,0.f,0.f,0.f);
    #pragma unroll
    for (int i = 0; i < 32; i += 4) {
        float4 x0 = p[(size_t)(i + 0) * 160];
        float4 x1 = p[(size_t)(i + 1) * 160];
        float4 x2 = p[(size_t)(i + 2) * 160];
        float4 x3 = p[(size_t)(i + 3) * 160];
        a0.x += x0.x; a0.y += x0.y; a0.z += x0.z; a0.w += x0.w;
        a1.x += x1.x; a1.y += x1.y; a1.z += x1.z; a1.w += x1.w;
        a2.x += x2.x; a2.y += x2.y; a2.z += x2.z; a2.w += x2.w;
        a3.x += x3.x; a3.y += x3.y; a3.z += x3.z; a3.w += x3.w;
    }
    float sx = (a0.x + a1.x) + (a2.x + a3.x);
    float sy = (a0.y + a1.y) + (a2.y + a3.y);
    float sz = (a0.z + a1.z) + (a2.z + a3.z);
    float sw = (a0.w + a1.w) + (a2.w + a3.w);

    float* dst = ksum + b * MM + c * 4;
    atomicAdd(dst + 0, sx);
    atomicAdd(dst + 1, sy);
    atomicAdd(dst + 2, sz);
    atomicAdd(dst + 3, sw);
}

// ---------------------------------------------------------------------------
// Robust tanh via rcp (exp of negative arg only -> never overflows)
// ---------------------------------------------------------------------------
__device__ __forceinline__ float tanh_rcp(float x) {
    float ax = fabsf(x);
    float e2 = __expf(-2.0f * ax);
    float th = (1.0f - e2) * __builtin_amdgcn_rcpf(1.0f + e2);
    return copysignf(th, x);
}

// ---------------------------------------------------------------------------
// Kernel 2: 1-WAVE blocks -> no __syncthreads, no vmcnt(0) drain ever.
// Wave-internal ordering: global->reg->ds_write gets compiler-COUNTED vmcnt
// (gradual drain); ds_write->ds_read gets lgkmcnt. Tile loop amortizes the
// ksum stage; `#pragma unroll 1` keeps VGPR flat (R13 lesson: 172 VGPR).
//   block = (b, hg, 64 t-rows) = 8 tiles x (8 rows x 16 heads).
//   tile:  5+5 coalesced f4 loads (16 lines/instr) -> LDS (pad 41)
//          -> 2 outputs/lane (row=lane&7, heads hq,hq+8) -> 32B-seg stores.
// ---------------------------------------------------------------------------
__global__ void __launch_bounds__(64)
attn_kernel(const float* __restrict__ q,
            const float* __restrict__ v,
            const float* __restrict__ ksum,
            float* __restrict__ out) {
    __shared__ float qs[8 * ROWSF];       // 5248 B
    __shared__ float vs[8 * ROWSF];       // 5248 B
    __shared__ float ks_lds[160];         // 640 B   (10.9 KB total -> 14/CU)

    const int lane = threadIdx.x;         // 0..63
    const int bid  = blockIdx.x;          // 0..4095
    const int part = bid & 63;            // 64 t-ranges per (b,hg)
    const int hg   = (bid >> 6) & 3;
    const int b    = bid >> 8;

    // ---- stage ksum slice (640B, one f4 per lane<40); no barrier needed ----
    if (lane < 40) {
        reinterpret_cast<float4*>(ks_lds)[lane] =
            reinterpret_cast<const float4*>(ksum + b * MM + hg * 160)[lane];
    }

    const int row = lane & 7;
    const int hq  = lane >> 3;            // 0..7; heads hq, hq+8

    // lane's 5 staging slots (tile = 8 rows x 40 f4)
    int srow[5], scol[5];
    #pragma unroll
    for (int j = 0; j < 5; ++j) {
        int s = lane + 64 * j;            // 0..319
        srow[j] = s / 40;
        scol[j] = s % 40;
    }

    // ksr from LDS (compiler inserts lgkmcnt wait after the stage above)
    const float R = 0.316227766016838f;   // 1/sqrt(10)
    float ksr[2][10];
    #pragma unroll
    for (int o = 0; o < 2; ++o)
        #pragma unroll
        for (int d = 0; d < 10; ++d)
            ksr[o][d] = ks_lds[(hq + 8 * o) * 10 + d] * R;

    const float4* qg0 = reinterpret_cast<const float4*>(q)
                      + (size_t)b * TT * 160 + hg * 40;
    const float4* vg0 = reinterpret_cast<const float4*>(v)
                      + (size_t)b * TT * 160 + hg * 40;
    float* ob0 = out + ((size_t)(b * HH + hg * 16 + hq)) * TT;

    float4* qs4 = reinterpret_cast<float4*>(qs);
    float4* vs4 = reinterpret_cast<float4*>(vs);

    #pragma unroll 1                      // keep registers flat across tiles
    for (int i = 0; i < 8; ++i) {
        const int t0 = part * 64 + i * 8;

        // ---- coalesced loads -> regs ----
        const float4* qg = qg0 + (size_t)t0 * 160;
        const float4* vg = vg0 + (size_t)t0 * 160;
        float4 rq[5], rv[5];
        #pragma unroll
        for (int j = 0; j < 5; ++j) {
            rq[j] = qg[srow[j] * 160 + scol[j]];
            rv[j] = vg[srow[j] * 160 + scol[j]];
        }
        // ---- LDS stage (counted vmcnt per ds_write; in-wave order safe) ----
        #pragma unroll
        for (int j = 0; j < 5; ++j) {
            qs4[srow[j] * PADF4 + scol[j]] = rq[j];
            vs4[srow[j] * PADF4 + scol[j]] = rv[j];
        }

        // ---- compute 2 outputs (compiler inserts lgkmcnt before reads) ----
        #pragma unroll
        for (int o = 0; o < 2; ++o) {
            const int fb = row * ROWSF + (hq + 8 * o) * 10;
            const float2* qp2 = reinterpret_cast<const float2*>(qs + fb);
            const float2* vp2 = reinterpret_cast<const float2*>(vs + fb);
            float sum = 0.f, dot = 0.f;
            #pragma unroll
            for (int p = 0; p < 5; ++p) {
                float2 qq = qp2[p];
                float2 vv = vp2[p];
                float e0 = __expf(tanh_rcp(qq.x * ksr[o][2*p]));
                float e1 = __expf(tanh_rcp(qq.y * ksr[o][2*p+1]));
                sum += e0 + e1;
                dot += e0 * vv.x + e1 * vv.y;
            }
            ob0[(size_t)(8 * o) * TT + t0 + row]
                = dot * __builtin_amdgcn_rcpf(sum);
        }
    }
}

// ---------------------------------------------------------------------------
extern "C" void kernel_launch(void* const* d_in, const int* in_sizes, int n_in,
                              void* d_out, int out_size, void* d_ws, size_t ws_size,
                              hipStream_t stream) {
    const float* q = (const float*)d_in[0];
    const float* k = (const float*)d_in[1];
    const float* v = (const float*)d_in[2];
    // d_in[3] = W, d_in[4] = b : dead code (softmax over size-1 axis == 1)
    float* out  = (float*)d_out;
    float* ksum = (float*)d_ws;    // B*M floats = 40 KB

    hipMemsetAsync(d_ws, 0, (size_t)BB * MM * sizeof(float), stream);
    ksum_kernel<<<dim3(10, 128), dim3(256), 0, stream>>>(k, ksum);
    // 16 b x 4 hg x 64 parts = 4096 one-wave blocks
    attn_kernel<<<dim3(4096), dim3(64), 0, stream>>>(q, v, ksum, out);
}

// Round 16
// 112.757 us; speedup vs baseline: 1.4719x; 1.1490x over previous
//
#include <hip/hip_runtime.h>
#include <stdint.h>

// Problem constants
#define BB 16
#define TT 4096
#define HH 64
#define MM 640    // HH*DD

#define TROWS 16          // t-rows per attn tile
#define PADF4 41          // LDS row stride in float4 (656 B)

// ---------------------------------------------------------------------------
// Kernel 1: ksum[b][m] = sum_t key[b][t][m]  (~27-30 us, near read roofline)
// ---------------------------------------------------------------------------
__global__ void __launch_bounds__(256)
ksum_kernel(const float* __restrict__ key, float* __restrict__ ksum) {
    int g = blockIdx.x * blockDim.x + threadIdx.x;   // b*160 + c
    int b = g / 160;
    int c = g % 160;
    int t0 = blockIdx.y * 32;

    const float4* p = reinterpret_cast<const float4*>(key)
                    + (size_t)b * TT * 160 + (size_t)t0 * 160 + c;

    float4 a0 = make_float4(0.f,0.f,0.f,0.f);
    float4 a1 = make_float4(0.f,0.f,0.f,0.f);
    float4 a2 = make_float4(0.f,0.f,0.f,0.f);
    float4 a3 = make_float4(0.f,0.f,0.f,0.f);
    #pragma unroll
    for (int i = 0; i < 32; i += 4) {
        float4 x0 = p[(size_t)(i + 0) * 160];
        float4 x1 = p[(size_t)(i + 1) * 160];
        float4 x2 = p[(size_t)(i + 2) * 160];
        float4 x3 = p[(size_t)(i + 3) * 160];
        a0.x += x0.x; a0.y += x0.y; a0.z += x0.z; a0.w += x0.w;
        a1.x += x1.x; a1.y += x1.y; a1.z += x1.z; a1.w += x1.w;
        a2.x += x2.x; a2.y += x2.y; a2.z += x2.z; a2.w += x2.w;
        a3.x += x3.x; a3.y += x3.y; a3.z += x3.z; a3.w += x3.w;
    }
    float sx = (a0.x + a1.x) + (a2.x + a3.x);
    float sy = (a0.y + a1.y) + (a2.y + a3.y);
    float sz = (a0.z + a1.z) + (a2.z + a3.z);
    float sw = (a0.w + a1.w) + (a2.w + a3.w);

    float* dst = ksum + b * MM + c * 4;
    atomicAdd(dst + 0, sx);
    atomicAdd(dst + 1, sy);
    atomicAdd(dst + 2, sz);
    atomicAdd(dst + 3, sw);
}

// ---------------------------------------------------------------------------
// Robust tanh via rcp (exp of negative arg only -> never overflows)
// ---------------------------------------------------------------------------
__device__ __forceinline__ float tanh_rcp(float x) {
    float ax = fabsf(x);
    float e2 = __expf(-2.0f * ax);
    float th = (1.0f - e2) * __builtin_amdgcn_rcpf(1.0f + e2);
    return copysignf(th, x);
}

// ---------------------------------------------------------------------------
// Kernel 2: CHAMPION structure (benched 112.9 us total, attn ~78 us),
// single change: hg is now the FASTEST grid dimension, so the 4 hg-sibling
// blocks sharing one 16-row x 2560B window are adjacent in dispatch ->
// co-resident -> their 640B slices combine into full contiguous page
// coverage at L2/DRAM.
//   - q/v: 10 coalesced float4/thread -> regs -> LDS (pad 41)
//   - ksum: one f4 instruction per block (tid<40) -> LDS; threads read
//           their head row from LDS (broadcast within 16-lane groups)
//   - compute: 2 (row, head) outputs per thread; 64B-segment stores
// ---------------------------------------------------------------------------
__global__ void __launch_bounds__(128)
attn_kernel(const float* __restrict__ q,
            const float* __restrict__ v,
            const float* __restrict__ ksum,
            float* __restrict__ out) {
    __shared__ float qs[TROWS * PADF4 * 4];
    __shared__ float vs[TROWS * PADF4 * 4];
    __shared__ float ks_lds[160];

    const int tid = threadIdx.x;          // 0..127
    const int hg  = blockIdx.x;           // FASTEST: hg siblings adjacent
    const int t0  = blockIdx.y * TROWS;
    const int b   = blockIdx.z;

    const float4* qg = reinterpret_cast<const float4*>(q)
                     + ((size_t)(b * TT + t0)) * 160 + hg * 40;
    const float4* vg = reinterpret_cast<const float4*>(v)
                     + ((size_t)(b * TT + t0)) * 160 + hg * 40;

    // ---- stage: 5+5 float4 into regs (back-to-back), plus ksum slice ----
    float4 rq[5], rv[5];
    #pragma unroll
    for (int j = 0; j < 5; ++j) {
        int idx = tid + 128 * j;          // 0..639
        int row = idx / 40;
        int c   = idx % 40;
        rq[j] = qg[(size_t)row * 160 + c];
        rv[j] = vg[(size_t)row * 160 + c];
    }
    if (tid < 40) {
        reinterpret_cast<float4*>(ks_lds)[tid] =
            reinterpret_cast<const float4*>(ksum + b * MM + hg * 160)[tid];
    }

    float4* qs4 = reinterpret_cast<float4*>(qs);
    float4* vs4 = reinterpret_cast<float4*>(vs);
    #pragma unroll
    for (int j = 0; j < 5; ++j) {
        int idx = tid + 128 * j;
        int row = idx / 40;
        int c   = idx % 40;
        qs4[row * PADF4 + c] = rq[j];
        vs4[row * PADF4 + c] = rv[j];
    }
    __syncthreads();

    // ---- per-thread ksum rows from LDS (broadcast within 16-lane groups) ----
    const float R = 0.316227766016838f;   // 1/sqrt(10)
    const int head0 = tid >> 4;           // 0..7 (second head = +8)
    const int row   = tid & 15;

    float ksr0[10], ksr1[10];
    #pragma unroll
    for (int d = 0; d < 10; ++d) {
        ksr0[d] = ks_lds[head0 * 10 + d] * R;
        ksr1[d] = ks_lds[(head0 + 8) * 10 + d] * R;
    }

    // ---- compute: 2 (row, head) outputs per thread ----
    #pragma unroll
    for (int o = 0; o < 2; ++o) {
        const int head  = head0 + o * 8;
        const int lbase = row * (PADF4 * 4) + head * 10;
        const float* kk = o ? ksr1 : ksr0;
        float sum = 0.f, dot = 0.f;
        #pragma unroll
        for (int d = 0; d < 10; ++d) {
            float e = __expf(tanh_rcp(qs[lbase + d] * kk[d]));
            sum += e;
            dot += e * vs[lbase + d];
        }
        out[((size_t)(b * HH + hg * 16 + head)) * TT + t0 + row]
            = dot * __builtin_amdgcn_rcpf(sum);
    }
}

// ---------------------------------------------------------------------------
extern "C" void kernel_launch(void* const* d_in, const int* in_sizes, int n_in,
                              void* d_out, int out_size, void* d_ws, size_t ws_size,
                              hipStream_t stream) {
    const float* q = (const float*)d_in[0];
    const float* k = (const float*)d_in[1];
    const float* v = (const float*)d_in[2];
    // d_in[3] = W, d_in[4] = b : dead code (softmax over size-1 axis == 1)
    float* out  = (float*)d_out;
    float* ksum = (float*)d_ws;    // B*M floats = 40 KB

    hipMemsetAsync(d_ws, 0, (size_t)BB * MM * sizeof(float), stream);
    ksum_kernel<<<dim3(10, 128), dim3(256), 0, stream>>>(k, ksum);
    // hg fastest, then t, then b
    attn_kernel<<<dim3(4, TT / TROWS, BB), dim3(128), 0, stream>>>(q, v, ksum, out);
}